// Round 1
// baseline (542.313 us; speedup 1.0000x reference)
//
#include <hip/hip_runtime.h>

#define NB 5   // N_BASIS
#define MD 5   // MAX_DELAY

// ---------------------------------------------------------------------------
// Setup kernels (once per launch)
// ---------------------------------------------------------------------------

// off[e] = (MD-1 - d)*N + n  where pre_idx[e] = d*N + n.
// Then at step t the gather address into zhist is simply t*N + off[e]:
//   zhist slot (t + 4 - d) holds z from step (t-1-d)  [slot u+MD = step u].
__global__ __launch_bounds__(256) void precompute_off_kernel(
    const int* __restrict__ pre_idx, int* __restrict__ offs, int E, int N)
{
    int e = blockIdx.x * blockDim.x + threadIdx.x;
    if (e >= E) return;
    int pre = pre_idx[e];
    int d = pre / N;
    int n = pre - d * N;
    offs[e] = (MD - 1 - d) * N + n;
}

__global__ __launch_bounds__(256) void init_v_kernel(
    const float* __restrict__ v_reset, float* __restrict__ v, int N)
{
    int n = blockIdx.x * blockDim.x + threadIdx.x;
    if (n < N) v[n] = v_reset[n];
}

// ---------------------------------------------------------------------------
// Per-step kernels
// ---------------------------------------------------------------------------

// Edge accumulation: i_rec[post*5+k] += z_pre * w_e * basis_e[k].
// z is exactly 0.0 or 1.0, so skip all work for silent pre-neurons.
__global__ __launch_bounds__(256) void edge_kernel(
    const int*   __restrict__ offs,
    const int*   __restrict__ post_idx,
    const float* __restrict__ weights,
    const float* __restrict__ edge_basis,
    const float* __restrict__ zhist_t,   // zhist + t*N  (5*N-wide window)
    float*       __restrict__ i_rec,
    int E)
{
    int e = blockIdx.x * blockDim.x + threadIdx.x;
    if (e >= E) return;
    float z = zhist_t[offs[e]];
    if (z != 0.0f) {
        float w = weights[e];
        int base = post_idx[e] * NB;
        #pragma unroll
        for (int k = 0; k < NB; ++k)
            atomicAdd(&i_rec[base + k], w * edge_basis[e * NB + k]);
    }
}

// Neuron update: psc recurrence, asc, membrane, spike, refractory.
// Also zeroes i_rec for the next step (saves a memset per step).
__global__ __launch_bounds__(256) void neuron_kernel(
    const float* __restrict__ x_t,          // ext_input + t*n5
    float*       __restrict__ psc,
    float*       __restrict__ i_rec,
    const float* __restrict__ syn_decay,
    const float* __restrict__ psc_initial,
    const float* __restrict__ decay,
    const float* __restrict__ current_factor,
    const float* __restrict__ gathered_g,
    const float* __restrict__ v_th,
    const float* __restrict__ v_reset,
    const float* __restrict__ normalizer,
    const float* __restrict__ t_ref,
    const float* __restrict__ exp_dt_k,     // (N,2)
    const float* __restrict__ asc_amps,     // (N,2)
    float*       __restrict__ v,
    float*       __restrict__ r,
    float*       __restrict__ asc,          // (N,2)
    const float* __restrict__ zprev,        // zhist + (t+4)*N : z of step t-1
    float*       __restrict__ znew,         // zhist + (t+5)*N : z of step t
    float*       __restrict__ out_t,        // out + t*N
    int N)
{
    int n = blockIdx.x * blockDim.x + threadIdx.x;
    if (n >= N) return;

    // psc recurrence + input current (sum k ascending, matches reference)
    float ic = 0.0f;
    int base = n * NB;
    #pragma unroll
    for (int k = 0; k < NB; ++k) {
        int idx = base + k;
        float p = psc[idx] * syn_decay[idx] + (i_rec[idx] + x_t[idx]) * psc_initial[idx];
        psc[idx] = p;
        i_rec[idx] = 0.0f;   // clear for next step
        ic += p;
    }

    float pz = zprev[n];

    float a0 = exp_dt_k[2 * n]     * asc[2 * n]     + pz * asc_amps[2 * n];
    float a1 = exp_dt_k[2 * n + 1] * asc[2 * n + 1] + pz * asc_amps[2 * n + 1];
    asc[2 * n]     = a0;
    asc[2 * n + 1] = a1;

    // c1 = input_current + asc.sum(-1) + g   (match reference association)
    float c1 = ic + (a0 + a1) + gathered_g[n];
    float nv = decay[n] * v[n] + current_factor[n] * c1;
    if (pz > 0.5f) nv = v_reset[n];

    float vsc = (nv - v_th[n]) / normalizer[n];
    float z = (vsc > 0.0f) ? 1.0f : 0.0f;
    float rr = r[n];
    if (rr > 0.0f) z = 0.0f;

    r[n] = fmaxf(rr + z * t_ref[n] - 1.0f, 0.0f);   // DT = 1.0
    v[n] = nv;
    znew[n]  = z;
    out_t[n] = z;
}

// ---------------------------------------------------------------------------
// Launcher
// ---------------------------------------------------------------------------

extern "C" void kernel_launch(void* const* d_in, const int* in_sizes, int n_in,
                              void* d_out, int out_size, void* d_ws, size_t ws_size,
                              hipStream_t stream)
{
    const float* weights        = (const float*)d_in[0];
    const float* edge_basis     = (const float*)d_in[1];
    const float* ext_input      = (const float*)d_in[2];
    const float* decay          = (const float*)d_in[3];
    const float* current_factor = (const float*)d_in[4];
    const float* gathered_g     = (const float*)d_in[5];
    const float* v_th           = (const float*)d_in[6];
    const float* v_reset        = (const float*)d_in[7];
    const float* normalizer     = (const float*)d_in[8];
    const float* t_ref          = (const float*)d_in[9];
    const float* exp_dt_k       = (const float*)d_in[10];
    const float* asc_amps       = (const float*)d_in[11];
    const float* syn_decay      = (const float*)d_in[12];
    const float* psc_initial    = (const float*)d_in[13];
    const int*   pre_idx        = (const int*)d_in[14];
    const int*   post_idx       = (const int*)d_in[15];

    const int E  = in_sizes[0];
    const int N  = in_sizes[3];
    const int n5 = N * NB;
    const int T  = in_sizes[2] / n5;   // B = 1

    float* out = (float*)d_out;

    // Workspace layout (floats unless noted):
    //  [ zhist (T+MD)*N | i_rec n5 | psc n5 | r N | asc 2N | v N | offs E(int) ]
    float* ws_f   = (float*)d_ws;
    float* zhist  = ws_f;                       size_t o = (size_t)(T + MD) * N;
    float* i_rec  = ws_f + o;                   o += n5;
    float* psc    = ws_f + o;                   o += n5;
    float* r      = ws_f + o;                   o += N;
    float* asc    = ws_f + o;                   o += 2 * N;
    float* v      = ws_f + o;                   o += N;
    int*   offs   = (int*)(ws_f + o);

    // Zero everything from zhist..asc in one memset:
    //   zhist (only first MD slots strictly need zeroing, but all written later
    //   slots are produced before they're consumed; zero the first MD*N plus
    //   i_rec/psc/r/asc contiguously).
    // zhist's slots >= MD are always written before read, so only zero MD*N of
    // it; but zhist is at the front, so do two memsets: one small for zhist
    // head, one for the state block.
    hipMemsetAsync(zhist, 0, (size_t)MD * N * sizeof(float), stream);
    size_t state_floats = (size_t)n5 + n5 + N + 2 * N;
    hipMemsetAsync(i_rec, 0, state_floats * sizeof(float), stream);

    init_v_kernel<<<(N + 255) / 256, 256, 0, stream>>>(v_reset, v, N);
    precompute_off_kernel<<<(E + 255) / 256, 256, 0, stream>>>(pre_idx, offs, E, N);

    for (int t = 0; t < T; ++t) {
        edge_kernel<<<(E + 255) / 256, 256, 0, stream>>>(
            offs, post_idx, weights, edge_basis,
            zhist + (size_t)t * N, i_rec, E);

        neuron_kernel<<<(N + 255) / 256, 256, 0, stream>>>(
            ext_input + (size_t)t * n5,
            psc, i_rec, syn_decay, psc_initial,
            decay, current_factor, gathered_g,
            v_th, v_reset, normalizer, t_ref,
            exp_dt_k, asc_amps,
            v, r, asc,
            zhist + (size_t)(t + MD - 1) * N,
            zhist + (size_t)(t + MD) * N,
            out + (size_t)t * N,
            N);
    }
}